// Round 3
// baseline (29011.346 us; speedup 1.0000x reference)
//
#include <hip/hip_runtime.h>
#include <math.h>

#define T_ 64
#define B_ 32
#define V_ 32000
#define H_ 1024
#define EMB_ 512
#define EPS_ 1e-7f
#define COPY_ID_ 3

typedef __bf16 bf16x8 __attribute__((ext_vector_type(8)));
typedef float f32x4 __attribute__((ext_vector_type(4)));

__device__ __forceinline__ unsigned short f2bf(float x) {
    union { float f; unsigned int i; } v; v.f = x;
    unsigned int r = v.i + 0x7FFF + ((v.i >> 16) & 1);
    return (unsigned short)(r >> 16);
}

// ---------------------------------------------------------------------------
// LSTM cell: one step, one layer. gates = [emb|xa|hprev] @ [Wih|Whh]^T + biases.
// All fp32. Grid: H/4 blocks; each block owns 4 hidden units (16 W rows).
// ---------------------------------------------------------------------------
__global__ __launch_bounds__(256) void lstm_cell_kernel(
    const float* __restrict__ E, const int* __restrict__ tokrow, int kx0,
    const float* __restrict__ xa, const float* __restrict__ hprev,
    const float* __restrict__ Wih, const float* __restrict__ Whh,
    const float* __restrict__ bih, const float* __restrict__ bhh,
    float* __restrict__ c_inout, float* __restrict__ h_out,
    float* __restrict__ hbuf_t)
{
    const int Kx   = kx0 + H_;        // columns of Wih
    const int Ktot = Kx + H_;
    const int u0  = blockIdx.x * 4;
    const int tid = threadIdx.x;
    __shared__ __align__(16) float As[32 * 68];
    __shared__ __align__(16) float Ws[16 * 68];
    __shared__ float Gacc[16 * 32];
    const int b = tid & 31, r0 = tid >> 5;
    float acc0 = 0.f, acc1 = 0.f;
    const int nch = Ktot >> 6;
    for (int ch = 0; ch < nch; ch++) {
        const int k0 = ch << 6;
        // stage A tile (32 x 64): region uniform per chunk (all bounds %64==0)
        #pragma unroll
        for (int i = 0; i < 8; i++) {
            int e = i * 256 + tid; int bb = e >> 6, kk = e & 63; int k = k0 + kk;
            float v;
            if (k0 < kx0)     v = E[(size_t)tokrow[bb] * EMB_ + k];
            else if (k0 < Kx) v = xa[bb * H_ + (k - kx0)];
            else              v = hprev[bb * H_ + (k - Kx)];
            As[bb * 68 + kk] = v;
        }
        // stage W tile (16 x 64)
        #pragma unroll
        for (int i = 0; i < 4; i++) {
            int e = i * 256 + tid; int rr = e >> 6, kk = e & 63; int k = k0 + kk;
            int j = (rr >> 2) * H_ + u0 + (rr & 3);
            float w = (k < Kx) ? Wih[(size_t)j * Kx + k]
                               : Whh[(size_t)j * H_ + (k - Kx)];
            Ws[rr * 68 + kk] = w;
        }
        __syncthreads();
        const float4* a4  = (const float4*)&As[b * 68];
        const float4* w4a = (const float4*)&Ws[r0 * 68];
        const float4* w4b = (const float4*)&Ws[(r0 + 8) * 68];
        #pragma unroll
        for (int q = 0; q < 16; q++) {
            float4 av = a4[q], wa = w4a[q], wb = w4b[q];
            acc0 += av.x * wa.x + av.y * wa.y + av.z * wa.z + av.w * wa.w;
            acc1 += av.x * wb.x + av.y * wb.y + av.z * wb.z + av.w * wb.w;
        }
        __syncthreads();
    }
    const int j0 = (r0 >> 2) * H_ + u0 + (r0 & 3);
    const int r1 = r0 + 8;
    const int j1 = (r1 >> 2) * H_ + u0 + (r1 & 3);
    Gacc[r0 * 32 + b] = acc0 + bih[j0] + bhh[j0];
    Gacc[r1 * 32 + b] = acc1 + bih[j1] + bhh[j1];
    __syncthreads();
    if (tid < 128) {
        int ul = tid >> 5, b2 = tid & 31;
        float gi = Gacc[(0 + ul) * 32 + b2];
        float gf = Gacc[(4 + ul) * 32 + b2];
        float gg = Gacc[(8 + ul) * 32 + b2];
        float go = Gacc[(12 + ul) * 32 + b2];
        int u = u0 + ul;
        float cold = c_inout[b2 * H_ + u];
        float si = 1.f / (1.f + __expf(-gi));
        float sf = 1.f / (1.f + __expf(-gf));
        float so = 1.f / (1.f + __expf(-go));
        float cn = sf * cold + si * tanhf(gg);
        float hn = so * tanhf(cn);
        c_inout[b2 * H_ + u] = cn;
        h_out[b2 * H_ + u] = hn;
        if (hbuf_t) hbuf_t[b2 * H_ + u] = hn;
    }
}

// ---------------------------------------------------------------------------
// Small GEMM: out[b, n0+r] = A[b,:K] . W[n0+r,:K] + bias.  M=32, NT=8 per block.
// All fp32. out leading dim = H_.
// ---------------------------------------------------------------------------
__global__ __launch_bounds__(256) void gemm32_kernel(
    const float* __restrict__ A, int K, const float* __restrict__ W,
    const float* __restrict__ bias, float* __restrict__ out)
{
    const int n0 = blockIdx.x * 8;
    const int tid = threadIdx.x;
    __shared__ __align__(16) float As[32 * 68];
    __shared__ __align__(16) float Ws[8 * 68];
    const int b = tid & 31, r = tid >> 5;
    float acc = 0.f;
    const int nch = K >> 6;
    for (int ch = 0; ch < nch; ch++) {
        const int k0 = ch << 6;
        #pragma unroll
        for (int i = 0; i < 8; i++) {
            int e = i * 256 + tid; int bb = e >> 6, kk = e & 63;
            As[bb * 68 + kk] = A[(size_t)bb * K + k0 + kk];
        }
        #pragma unroll
        for (int i = 0; i < 2; i++) {
            int e = i * 256 + tid; int rr = e >> 6, kk = e & 63;
            Ws[rr * 68 + kk] = W[(size_t)(n0 + rr) * K + k0 + kk];
        }
        __syncthreads();
        const float4* a4 = (const float4*)&As[b * 68];
        const float4* w4 = (const float4*)&Ws[r * 68];
        #pragma unroll
        for (int q = 0; q < 16; q++) {
            float4 av = a4[q], wv = w4[q];
            acc += av.x * wv.x + av.y * wv.y + av.z * wv.z + av.w * wv.w;
        }
        __syncthreads();
    }
    out[b * H_ + n0 + r] = acc + bias[n0 + r];
}

// ---------------------------------------------------------------------------
// Attention for step t: scores over s<=t, softmax, summary; writes dist row and
// cat = [htop | summary]. Grid: B blocks.
// ---------------------------------------------------------------------------
__global__ __launch_bounds__(256) void attn_kernel(
    int t, const float* __restrict__ hbuf, const float* __restrict__ keybuf,
    const int* __restrict__ tokens, float* __restrict__ dist_all,
    float* __restrict__ cat)
{
    const int bb = blockIdx.x;
    const int tid = threadIdx.x;
    __shared__ float ht[H_];
    __shared__ float sc[T_];
    __shared__ float dsh[T_];
    for (int k = tid; k < H_; k += 256)
        ht[k] = hbuf[((size_t)t * B_ + bb) * H_ + k];
    __syncthreads();
    const int wave = tid >> 6, lane = tid & 63;
    for (int s = wave; s <= t; s += 4) {
        const float* kv = keybuf + ((size_t)s * B_ + bb) * H_;
        float p = 0.f;
        #pragma unroll
        for (int j = 0; j < 16; j++) p += kv[lane + 64 * j] * ht[lane + 64 * j];
        #pragma unroll
        for (int off = 32; off > 0; off >>= 1) p += __shfl_down(p, off, 64);
        if (lane == 0) {
            float pen = (tokens[s * B_ + bb] == 0) ? -99999.0f : 0.0f;
            sc[s] = p + pen;
        }
    }
    __syncthreads();
    if (tid < 64) {
        float v = (tid <= t) ? sc[tid] : -1e30f;
        float m = v;
        #pragma unroll
        for (int off = 32; off > 0; off >>= 1) m = fmaxf(m, __shfl_down(m, off, 64));
        m = __shfl(m, 0, 64);
        float e = (tid <= t) ? __expf(v - m) : 0.f;
        float ss = e;
        #pragma unroll
        for (int off = 32; off > 0; off >>= 1) ss += __shfl_down(ss, off, 64);
        ss = __shfl(ss, 0, 64);
        float d = e / ss;
        dsh[tid] = d;
        if (tid <= t) dist_all[((size_t)t * T_ + tid) * B_ + bb] = d;
    }
    __syncthreads();
    float sm0 = 0.f, sm1 = 0.f, sm2 = 0.f, sm3 = 0.f;
    for (int s = 0; s <= t; s++) {
        const float d = dsh[s];
        const float* hr = hbuf + ((size_t)s * B_ + bb) * H_;
        sm0 += d * hr[tid];
        sm1 += d * hr[tid + 256];
        sm2 += d * hr[tid + 512];
        sm3 += d * hr[tid + 768];
    }
    float* cb = cat + (size_t)bb * (2 * H_);
    cb[H_ + tid]       = sm0;
    cb[H_ + tid + 256] = sm1;
    cb[H_ + tid + 512] = sm2;
    cb[H_ + tid + 768] = sm3;
    cb[tid]       = ht[tid];
    cb[tid + 256] = ht[tid + 256];
    cb[tid + 512] = ht[tid + 512];
    cb[tid + 768] = ht[tid + 768];
}

// ---------------------------------------------------------------------------
// fp32 -> bf16 cast (n4 float4 groups)
// ---------------------------------------------------------------------------
__global__ __launch_bounds__(256) void cast_bf16_kernel(
    const float* __restrict__ src, unsigned short* __restrict__ dst, int n4)
{
    int idx = blockIdx.x * 256 + threadIdx.x;
    int stride = gridDim.x * 256;
    for (int i = idx; i < n4; i += stride) {
        float4 v = ((const float4*)src)[i];
        ushort4 o;
        o.x = f2bf(v.x); o.y = f2bf(v.y); o.z = f2bf(v.z); o.w = f2bf(v.w);
        ((ushort4*)dst)[i] = o;
    }
}

// ---------------------------------------------------------------------------
// Logits GEMM: (2048 x 1024) @ Wp^T (32000 x 1024) + bp, bf16 MFMA 16x16x32.
// Block tile 128x128, 4 waves 2x2, each wave 4x4 MFMA tiles. Writes FP32
// logits into d_out.
// ---------------------------------------------------------------------------
__global__ __launch_bounds__(256) void logits_mfma_kernel(
    const __bf16* __restrict__ Abf, const __bf16* __restrict__ Bbf,
    const float* __restrict__ bp, float* __restrict__ out)
{
    __shared__ __align__(16) __bf16 As[128 * 32];
    __shared__ __align__(16) __bf16 Bs[128 * 32];
    const int tid = threadIdx.x;
    const int lane = tid & 63;
    const int wave = tid >> 6;
    const int quad = lane >> 4, l15 = lane & 15;
    const int m0 = blockIdx.y * 128, n0 = blockIdx.x * 128;
    const int wm = wave >> 1, wn = wave & 1;
    const f32x4 vzero = {0.f, 0.f, 0.f, 0.f};
    f32x4 acc[4][4];
    #pragma unroll
    for (int mt = 0; mt < 4; mt++)
        #pragma unroll
        for (int nt = 0; nt < 4; nt++) acc[mt][nt] = vzero;

    for (int k0 = 0; k0 < 1024; k0 += 32) {
        #pragma unroll
        for (int i = 0; i < 2; i++) {
            int idx = i * 256 + tid;
            int row = idx >> 2, co = (idx & 3) * 8;
            ((uint4*)As)[idx] = *(const uint4*)(Abf + (size_t)(m0 + row) * 1024 + k0 + co);
            ((uint4*)Bs)[idx] = *(const uint4*)(Bbf + (size_t)(n0 + row) * 1024 + k0 + co);
        }
        __syncthreads();
        bf16x8 af[4], bfr[4];
        #pragma unroll
        for (int mt = 0; mt < 4; mt++)
            af[mt] = *(const bf16x8*)&As[(wm * 64 + mt * 16 + l15) * 32 + quad * 8];
        #pragma unroll
        for (int nt = 0; nt < 4; nt++)
            bfr[nt] = *(const bf16x8*)&Bs[(wn * 64 + nt * 16 + l15) * 32 + quad * 8];
        #pragma unroll
        for (int mt = 0; mt < 4; mt++)
            #pragma unroll
            for (int nt = 0; nt < 4; nt++)
                acc[mt][nt] = __builtin_amdgcn_mfma_f32_16x16x32_bf16(
                    af[mt], bfr[nt], acc[mt][nt], 0, 0, 0);
        __syncthreads();
    }
    // C/D layout: col = lane&15, row = (lane>>4)*4 + reg   [m89-verified]
    #pragma unroll
    for (int mt = 0; mt < 4; mt++) {
        #pragma unroll
        for (int nt = 0; nt < 4; nt++) {
            int gcol = n0 + wn * 64 + nt * 16 + l15;
            int growb = m0 + wm * 64 + mt * 16 + quad * 4;
            float bpv = bp[gcol];
            #pragma unroll
            for (int rr = 0; rr < 4; rr++)
                out[(size_t)(growb + rr) * V_ + gcol] = acc[mt][nt][rr] + bpv;
        }
    }
}

// ---------------------------------------------------------------------------
// Per-row max / sumexp / copy-weight from fp32 logits. Grid: T*B blocks.
// ---------------------------------------------------------------------------
__global__ __launch_bounds__(256) void rowstats_kernel(
    const float* __restrict__ logits, float* __restrict__ stats)
{
    const int row = blockIdx.x; const int tid = threadIdx.x;
    const float4* p4 = (const float4*)(logits + (size_t)row * V_);
    __shared__ float red[8];
    const int lane = tid & 63, wave = tid >> 6;
    float m = -1e30f;
    for (int i = tid; i < V_ / 4; i += 256) {
        float4 u = p4[i];
        m = fmaxf(m, fmaxf(fmaxf(u.x, u.y), fmaxf(u.z, u.w)));
    }
    #pragma unroll
    for (int off = 32; off > 0; off >>= 1) m = fmaxf(m, __shfl_down(m, off, 64));
    if (lane == 0) red[wave] = m;
    __syncthreads();
    if (tid == 0) {
        float mm = red[0];
        for (int w = 1; w < 4; w++) mm = fmaxf(mm, red[w]);
        red[4] = mm;
    }
    __syncthreads();
    const float M = red[4];
    float s = 0.f;
    for (int i = tid; i < V_ / 4; i += 256) {
        float4 u = p4[i];
        s += __expf(u.x - M) + __expf(u.y - M) + __expf(u.z - M) + __expf(u.w - M);
    }
    #pragma unroll
    for (int off = 32; off > 0; off >>= 1) s += __shfl_down(s, off, 64);
    if (lane == 0) red[wave] = s;
    __syncthreads();
    if (tid == 0) {
        float S = red[0] + red[1] + red[2] + red[3];
        float lc = logits[(size_t)row * V_ + COPY_ID_];
        float cw = __expf(lc - M) / S;
        stats[row * 4 + 0] = M;
        stats[row * 4 + 1] = S;
        stats[row * 4 + 2] = cw;
    }
}

// ---------------------------------------------------------------------------
// Fixups for scattered copy tokens: computed from PRISTINE logits (before the
// bulk finalize overwrites them). Grid: T*B blocks x T threads.
// ---------------------------------------------------------------------------
__global__ __launch_bounds__(64) void fixup_compute_kernel(
    const float* __restrict__ logits, const float* __restrict__ stats,
    const int* __restrict__ tokens, const float* __restrict__ dist_all,
    float* __restrict__ fixval)
{
    const int bid = blockIdx.x;          // t*B + b
    const int t = bid >> 5, b = bid & 31;
    const int s = threadIdx.x;
    if (s > t) return;
    const int v = tokens[s * B_ + b];
    float d = 0.f;
    for (int s2 = 0; s2 <= t; s2++)
        if (tokens[s2 * B_ + b] == v)
            d += dist_all[((size_t)t * T_ + s2) * B_ + b];
    const float M = stats[bid * 4], S = stats[bid * 4 + 1], cw = stats[bid * 4 + 2];
    const float l = logits[(size_t)bid * V_ + v];
    const float p = __expf(l - M) / S;
    fixval[((size_t)t * T_ + s) * B_ + b] = __logf(cw * (EPS_ + d) + (1.f - cw) * p);
}

// ---------------------------------------------------------------------------
// Bulk finalize in place: out = log((1-cw)*softmax + cw*EPS). Grid: T*B blocks.
// ---------------------------------------------------------------------------
__global__ __launch_bounds__(256) void finalize_kernel(
    float* __restrict__ logits, const float* __restrict__ stats)
{
    const int row = blockIdx.x; const int tid = threadIdx.x;
    float4* p4 = (float4*)(logits + (size_t)row * V_);
    const float M = stats[row * 4], S = stats[row * 4 + 1], cw = stats[row * 4 + 2];
    const float inv = 1.f / S, omc = 1.f - cw, ce = cw * EPS_;
    for (int i = tid; i < V_ / 4; i += 256) {
        float4 u = p4[i];
        u.x = __logf(omc * (__expf(u.x - M) * inv) + ce);
        u.y = __logf(omc * (__expf(u.y - M) * inv) + ce);
        u.z = __logf(omc * (__expf(u.z - M) * inv) + ce);
        u.w = __logf(omc * (__expf(u.w - M) * inv) + ce);
        p4[i] = u;
    }
}

__global__ __launch_bounds__(64) void fixup_apply_kernel(
    float* __restrict__ logits, const int* __restrict__ tokens,
    const float* __restrict__ fixval)
{
    const int bid = blockIdx.x; const int t = bid >> 5, b = bid & 31;
    const int s = threadIdx.x;
    if (s > t) return;
    const int v = tokens[s * B_ + b];
    logits[(size_t)bid * V_ + v] = fixval[((size_t)t * T_ + s) * B_ + b];
}

// ---------------------------------------------------------------------------
extern "C" void kernel_launch(void* const* d_in, const int* in_sizes, int n_in,
                              void* d_out, int out_size, void* d_ws, size_t ws_size,
                              hipStream_t stream)
{
    const int*   tok  = (const int*)d_in[0];
    const float* h0i  = (const float*)d_in[1];
    const float* c0i  = (const float*)d_in[2];
    const float* E    = (const float*)d_in[3];
    const float* Wih0 = (const float*)d_in[4];
    const float* Whh0 = (const float*)d_in[5];
    const float* bih0 = (const float*)d_in[6];
    const float* bhh0 = (const float*)d_in[7];
    const float* Wih1 = (const float*)d_in[8];
    const float* Whh1 = (const float*)d_in[9];
    const float* bih1 = (const float*)d_in[10];
    const float* bhh1 = (const float*)d_in[11];
    const float* Wk   = (const float*)d_in[12];
    const float* bk   = (const float*)d_in[13];
    const float* Wc   = (const float*)d_in[14];
    const float* bc   = (const float*)d_in[15];
    const float* Wp   = (const float*)d_in[16];
    const float* bp   = (const float*)d_in[17];
    float* out = (float*)d_out;

    float* ws = (float*)d_ws;
    size_t off = 0;
    float* hbuf   = ws + off; off += (size_t)T_ * B_ * H_;     // 2M floats
    float* keybuf = ws + off; off += (size_t)T_ * B_ * H_;     // 2M
    float* comb   = ws + off; off += (size_t)T_ * B_ * H_;     // 2M
    float* dist   = ws + off; off += (size_t)T_ * T_ * B_;     // 128K
    float* fixv   = ws + off; off += (size_t)T_ * T_ * B_;     // 128K
    float* cat    = ws + off; off += (size_t)B_ * 2 * H_;      // 64K
    float* h0p0   = ws + off; off += B_ * H_;
    float* h0p1   = ws + off; off += B_ * H_;
    float* h1p0   = ws + off; off += B_ * H_;
    float* h1p1   = ws + off; off += B_ * H_;
    float* c0b    = ws + off; off += B_ * H_;
    float* c1b    = ws + off; off += B_ * H_;
    float* zfeed  = ws + off; off += B_ * H_;
    float* stats  = ws + off; off += (size_t)T_ * B_ * 4;
    unsigned short* combbf = (unsigned short*)(ws + off); off += (size_t)T_ * B_ * H_ / 2;
    unsigned short* Wpbf   = (unsigned short*)(ws + off); off += (size_t)V_ * H_ / 2;

    hipMemsetAsync(zfeed, 0, B_ * H_ * sizeof(float), stream);
    hipMemcpyAsync(h0p0, h0i,           B_ * H_ * 4, hipMemcpyDeviceToDevice, stream);
    hipMemcpyAsync(h1p0, h0i + B_ * H_, B_ * H_ * 4, hipMemcpyDeviceToDevice, stream);
    hipMemcpyAsync(c0b,  c0i,           B_ * H_ * 4, hipMemcpyDeviceToDevice, stream);
    hipMemcpyAsync(c1b,  c0i + B_ * H_, B_ * H_ * 4, hipMemcpyDeviceToDevice, stream);

    float* h0p[2] = {h0p0, h0p1};
    float* h1p[2] = {h1p0, h1p1};

    for (int t = 0; t < T_; t++) {
        const float* feed = (t == 0) ? zfeed : (comb + (size_t)(t - 1) * B_ * H_);
        lstm_cell_kernel<<<H_ / 4, 256, 0, stream>>>(
            E, tok + t * B_, EMB_, feed, h0p[t & 1],
            Wih0, Whh0, bih0, bhh0, c0b, h0p[(t + 1) & 1], nullptr);
        lstm_cell_kernel<<<H_ / 4, 256, 0, stream>>>(
            nullptr, nullptr, 0, h0p[(t + 1) & 1], h1p[t & 1],
            Wih1, Whh1, bih1, bhh1, c1b, h1p[(t + 1) & 1],
            hbuf + (size_t)t * B_ * H_);
        gemm32_kernel<<<H_ / 8, 256, 0, stream>>>(
            hbuf + (size_t)t * B_ * H_, H_, Wk, bk, keybuf + (size_t)t * B_ * H_);
        attn_kernel<<<B_, 256, 0, stream>>>(t, hbuf, keybuf, tok, dist, cat);
        gemm32_kernel<<<H_ / 8, 256, 0, stream>>>(
            cat, 2 * H_, Wc, bc, comb + (size_t)t * B_ * H_);
    }

    cast_bf16_kernel<<<512, 256, 0, stream>>>(comb, combbf, T_ * B_ * H_ / 4);
    cast_bf16_kernel<<<2048, 256, 0, stream>>>(Wp, Wpbf, V_ * H_ / 4);
    dim3 g1(V_ / 128, (T_ * B_) / 128);
    logits_mfma_kernel<<<g1, 256, 0, stream>>>(
        (const __bf16*)combbf, (const __bf16*)Wpbf, bp, out);
    rowstats_kernel<<<T_ * B_, 256, 0, stream>>>(out, stats);
    fixup_compute_kernel<<<T_ * B_, T_, 0, stream>>>(out, stats, tok, dist, fixv);
    finalize_kernel<<<T_ * B_, 256, 0, stream>>>(out, stats);
    fixup_apply_kernel<<<T_ * B_, T_, 0, stream>>>(out, tok, fixv);
}